// Round 1
// baseline (137.303 us; speedup 1.0000x reference)
//
#include <hip/hip_runtime.h>
#include <math.h>

#define FEAT 64
#define SEGS_PER_BLOCK 4

__device__ __forceinline__ int lower_bound(const int* __restrict__ a, int n, int key) {
    int lo = 0, hi = n;
    while (lo < hi) {
        int mid = (lo + hi) >> 1;
        int v = a[mid];
        if (v < key) lo = mid + 1; else hi = mid;
    }
    return lo;
}

__global__ __launch_bounds__(64 * SEGS_PER_BLOCK)
void HyperedgeMaxAggregator_kernel(const float* __restrict__ features,
                                   const int* __restrict__ node_ids,
                                   const int* __restrict__ segment_ids,
                                   float* __restrict__ out,
                                   int n_members, int num_segments) {
    const int wave = threadIdx.x >> 6;
    const int lane = threadIdx.x & 63;
    const int seg  = blockIdx.x * SEGS_PER_BLOCK + wave;
    if (seg >= num_segments) return;

    // Segment run boundaries in the sorted segment_ids array (wave-uniform).
    const int start = lower_bound(segment_ids, n_members, seg);
    const int end   = lower_bound(segment_ids, n_members, seg + 1);

    // Lane = feature dim. Each member row is a coalesced 256B load.
    float acc0 = -INFINITY, acc1 = -INFINITY;
    int j = start;
    for (; j + 1 < end; j += 2) {
        const int n0 = node_ids[j];
        const int n1 = node_ids[j + 1];
        const float v0 = features[(size_t)n0 * FEAT + lane];
        const float v1 = features[(size_t)n1 * FEAT + lane];
        acc0 = fmaxf(acc0, v0);
        acc1 = fmaxf(acc1, v1);
    }
    if (j < end) {
        acc0 = fmaxf(acc0, features[(size_t)node_ids[j] * FEAT + lane]);
    }
    out[(size_t)seg * FEAT + lane] = fmaxf(acc0, acc1);
}

extern "C" void kernel_launch(void* const* d_in, const int* in_sizes, int n_in,
                              void* d_out, int out_size, void* d_ws, size_t ws_size,
                              hipStream_t stream) {
    const float* features    = (const float*)d_in[0];
    const int*   node_ids    = (const int*)d_in[1];
    const int*   segment_ids = (const int*)d_in[2];
    // d_in[3] is num_segments on device; derive it on host from out_size.
    float* out = (float*)d_out;

    const int n_members    = in_sizes[1];
    const int num_segments = out_size / FEAT;

    const int blocks = (num_segments + SEGS_PER_BLOCK - 1) / SEGS_PER_BLOCK;
    HyperedgeMaxAggregator_kernel<<<blocks, 64 * SEGS_PER_BLOCK, 0, stream>>>(
        features, node_ids, segment_ids, out, n_members, num_segments);
}

// Round 2
// 46.110 us; speedup vs baseline: 2.9777x; 2.9777x over previous
//
#include <hip/hip_runtime.h>
#include <math.h>

#define FEAT 64
#define SEGS_PER_BLOCK 4

__device__ __forceinline__ float4 fmax4(float4 a, float4 b) {
    return make_float4(fmaxf(a.x, b.x), fmaxf(a.y, b.y),
                       fmaxf(a.z, b.z), fmaxf(a.w, b.w));
}

// Pre-pass: segment_ids is sorted; thread j fills starts[s] for every segment s
// whose run begins at j (covers empty segments via the gap loop).
__global__ __launch_bounds__(256)
void seg_starts_kernel(const int* __restrict__ segment_ids,
                       int* __restrict__ starts,
                       int n_members, int num_segments) {
    const int j = blockIdx.x * blockDim.x + threadIdx.x;
    if (j >= n_members) return;
    const int sj = segment_ids[j];
    const int sp = (j == 0) ? -1 : segment_ids[j - 1];
    for (int s = sp + 1; s <= sj; ++s) starts[s] = j;
    if (j == n_members - 1) {
        for (int s = sj + 1; s <= num_segments; ++s) starts[s] = n_members;
    }
}

// Main: one wave per segment. lane&15 = feature-quad (float4), lane>>4 = member
// slot -> 4 member rows in flight per iteration, unroll 2 -> 8 outstanding loads.
__global__ __launch_bounds__(64 * SEGS_PER_BLOCK)
void HyperedgeMaxAggregator_kernel(const float* __restrict__ features,
                                   const int* __restrict__ node_ids,
                                   const int* __restrict__ starts,
                                   float* __restrict__ out,
                                   int num_segments) {
    const int wave = threadIdx.x >> 6;
    const int lane = threadIdx.x & 63;
    const int seg  = blockIdx.x * SEGS_PER_BLOCK + wave;
    if (seg >= num_segments) return;

    const int start = starts[seg];
    const int end   = starts[seg + 1];

    const int mslot = lane >> 4;          // member slot 0..3
    const int fq    = (lane & 15) << 2;   // feature offset (float4)

    float4 acc = make_float4(-INFINITY, -INFINITY, -INFINITY, -INFINITY);

    int j = start + mslot;
    for (; j + 4 < end; j += 8) {
        const int n0 = node_ids[j];
        const int n1 = node_ids[j + 4];
        const float4 v0 = *(const float4*)(features + (size_t)n0 * FEAT + fq);
        const float4 v1 = *(const float4*)(features + (size_t)n1 * FEAT + fq);
        acc = fmax4(acc, v0);
        acc = fmax4(acc, v1);
    }
    if (j < end) {
        const int n0 = node_ids[j];
        const float4 v0 = *(const float4*)(features + (size_t)n0 * FEAT + fq);
        acc = fmax4(acc, v0);
    }

    // Reduce across the 4 member slots (lanes differing in bits 4-5).
    acc.x = fmaxf(acc.x, __shfl_xor(acc.x, 16, 64));
    acc.y = fmaxf(acc.y, __shfl_xor(acc.y, 16, 64));
    acc.z = fmaxf(acc.z, __shfl_xor(acc.z, 16, 64));
    acc.w = fmaxf(acc.w, __shfl_xor(acc.w, 16, 64));
    acc.x = fmaxf(acc.x, __shfl_xor(acc.x, 32, 64));
    acc.y = fmaxf(acc.y, __shfl_xor(acc.y, 32, 64));
    acc.z = fmaxf(acc.z, __shfl_xor(acc.z, 32, 64));
    acc.w = fmaxf(acc.w, __shfl_xor(acc.w, 32, 64));

    if (lane < 16) {
        *(float4*)(out + (size_t)seg * FEAT + fq) = acc;
    }
}

extern "C" void kernel_launch(void* const* d_in, const int* in_sizes, int n_in,
                              void* d_out, int out_size, void* d_ws, size_t ws_size,
                              hipStream_t stream) {
    const float* features    = (const float*)d_in[0];
    const int*   node_ids    = (const int*)d_in[1];
    const int*   segment_ids = (const int*)d_in[2];
    float* out = (float*)d_out;

    const int n_members    = in_sizes[1];
    const int num_segments = out_size / FEAT;

    int* starts = (int*)d_ws;  // (num_segments + 1) ints = ~200 KB

    seg_starts_kernel<<<(n_members + 255) / 256, 256, 0, stream>>>(
        segment_ids, starts, n_members, num_segments);

    const int blocks = (num_segments + SEGS_PER_BLOCK - 1) / SEGS_PER_BLOCK;
    HyperedgeMaxAggregator_kernel<<<blocks, 64 * SEGS_PER_BLOCK, 0, stream>>>(
        features, node_ids, starts, out, num_segments);
}